// Round 1
// baseline (196.538 us; speedup 1.0000x reference)
//
#include <hip/hip_runtime.h>
#include <cstdint>

// Problem constants (fixed by the reference)
#define BATCH  64
#define NATOMS 1024
#define DEG    5
#define FIN    256
#define OOUT   256
#define NBF    6
#define KDIM   262          // FIN + NBF
#define NKT    9            // k-tiles of 32 (K padded to 288)
#define MROWS  (BATCH * NATOMS)   // 65536
#define MT     32           // atom rows per block (fused kernel)
#define AS     296          // Afeat LDS row stride in shorts (37*8: 16B-aligned)

#define FRAG_SHORTS (16 * NKT * 64 * 8)   // 73,728 shorts (147,456 B) per degree

typedef __attribute__((ext_vector_type(8))) short bf16x8;   // MFMA A/B frag (4 VGPR)
typedef __attribute__((ext_vector_type(4))) float f32x4;    // MFMA C/D frag

__device__ __forceinline__ unsigned short f2bf(float x) {
    unsigned u = __float_as_uint(x);
    u += 0x7fff + ((u >> 16) & 1);          // round-to-nearest-even
    return (unsigned short)(u >> 16);
}
__device__ __forceinline__ float bf2f(unsigned short h) {
    return __uint_as_float(((unsigned)h) << 16);
}
__device__ __forceinline__ float sigmoidf_(float x) {
    return 1.f / (1.f + __expf(-x));
}

// ---------------------------------------------------------------------------
// Kernel 1: pre-swizzle degW into MFMA B-fragment lane order (bf16).
// all6=1: all 6 degrees, layout [d][g][t][lane][8]  (864 KB, L2-resident)
// all6=0: degree-5 only at offset 0 (legacy 147 KB layout)
// ---------------------------------------------------------------------------
__global__ __launch_bounds__(256)
void convert_w_kernel(const float* __restrict__ degW, unsigned short* __restrict__ Wsw,
                      int all6)
{
    const int total = (all6 ? 6 : 1) * 16 * NKT * 64;
    const int idx = blockIdx.x * 256 + threadIdx.x;
    if (idx >= total) return;
    const int lane = idx & 63;
    int r = idx >> 6;
    const int t = r % NKT; r /= NKT;
    const int g = r & 15;
    const int d = r >> 4;
    const int srcd = all6 ? d : DEG;
    const int col  = g * 16 + (lane & 15);
    const int k0   = t * 32 + (lane >> 4) * 8;
    const float* __restrict__ W = degW + (size_t)srcd * KDIM * OOUT;
    unsigned short* dst = Wsw + (size_t)idx * 8;
    #pragma unroll
    for (int j = 0; j < 8; ++j) {
        const int k = k0 + j;
        dst[j] = f2bf((k < KDIM) ? W[(size_t)k * OOUT + col] : 0.f);
    }
}

// ---------------------------------------------------------------------------
// Kernel 2: fused gather + bf16 MFMA GEMM + odd-degree handling.
// R7: latency-exposure fixes —
//   gather: 3-row chunks (18 float4 loads in flight; reg budget 84->~115 is
//           free occupancy-wise since 4 waves/SIMD holds up to 128)
//   mfma:   A-frag (LDS) double-buffer added next to the B-frag one;
//           first B-frags hoisted above the barrier
//   fixup:  serial fp32 dot-chain replaced by masked MFMA re-pass with
//           pre-swizzled Wsw[d] (removes the straggler tail)
//   bonds:  one ushort4 zero-fill + 48-lane strided sum (was 4 masked iters)
// ---------------------------------------------------------------------------
__global__ __launch_bounds__(256, 4)
void nfp_fused_kernel(const float* __restrict__ atoms, const float* __restrict__ bonds,
                      const int* __restrict__ edges, const unsigned short* __restrict__ Wsw,
                      const float* __restrict__ degW, const float* __restrict__ bias,
                      float* __restrict__ out, int all6)
{
    __shared__ short Afeat[MT * AS];     // 18,944 B
    __shared__ int   edg[MT * DEG];      // 160 entries
    __shared__ int   deg_lds[MT];
    __shared__ int   degmask;

    const int tid  = threadIdx.x;
    const int lane = tid & 63;
    const int wave = tid >> 6;

    // XCD-aware mapping: 32 blocks per batch; batch b -> XCD b%8 (heuristic).
    const int bid   = blockIdx.x;                 // 2048 blocks
    const int xcd   = bid & 7;
    const int per   = bid >> 3;                   // 0..255 within XCD
    const int batch = (per >> 5) * 8 + xcd;       // 8 batch-groups of 8
    const int blk   = per & 31;
    const int row0  = batch * NATOMS + blk * MT;

    // ---- stage edges (MT*DEG = 160 <= 256: single shot) ----
    if (tid == 0) degmask = 0;
    if (tid < MT * DEG) edg[tid] = edges[row0 * DEG + tid];
    __syncthreads();
    if (tid < MT) {
        int dc = 0;
        #pragma unroll
        for (int d = 0; d < DEG; ++d) dc += (edg[tid * DEG + d] != -1) ? 1 : 0;
        deg_lds[tid] = dc;
        atomicOr(&degmask, 1 << dc);
    }

    // ---- gather: wave w owns rows [w*8, w*8+8); 3+3+2 row chunks ----
    const float* __restrict__ abase = atoms + ((size_t)batch << 10) * FIN;
    const int selfrow = blk * MT;                 // row offset within batch
    const int mw = wave * 8;

#define GATHER_CHUNK(MB, NR)                                                          \
    {                                                                                 \
        float4 self[NR]; float4 nv[NR][DEG]; int msk[NR];                             \
        _Pragma("unroll")                                                             \
        for (int r = 0; r < NR; ++r) {                                                \
            const int m = (MB) + r;                                                   \
            msk[r] = 0;                                                               \
            self[r] = *(const float4*)&abase[(size_t)(selfrow + m) * FIN + lane * 4]; \
            _Pragma("unroll")                                                         \
            for (int d = 0; d < DEG; ++d) {                                           \
                const int e = edg[m * DEG + d];                                       \
                msk[r] |= (e >= 0) ? (1 << d) : 0;                                    \
                const int ei = (e >= 0) ? e : 0;      /* clamped (always legal) */    \
                nv[r][d] = *(const float4*)&abase[(size_t)ei * FIN + lane * 4];       \
            }                                                                         \
        }                                                                             \
        _Pragma("unroll")                                                             \
        for (int r = 0; r < NR; ++r) {                                                \
            const int m = (MB) + r;                                                   \
            float4 v = self[r];                                                       \
            _Pragma("unroll")                                                         \
            for (int d = 0; d < DEG; ++d) {                                           \
                const float fl = ((msk[r] >> d) & 1) ? 1.f : 0.f;                     \
                v.x += fl * nv[r][d].x; v.y += fl * nv[r][d].y;                       \
                v.z += fl * nv[r][d].z; v.w += fl * nv[r][d].w;                       \
            }                                                                         \
            ushort4 us;                                                               \
            us.x = f2bf(v.x); us.y = f2bf(v.y); us.z = f2bf(v.z); us.w = f2bf(v.w);   \
            *(ushort4*)&Afeat[m * AS + lane * 4] = us;                                \
        }                                                                             \
    }

    GATHER_CHUNK(mw + 0, 3)
    GATHER_CHUNK(mw + 3, 3)
    GATHER_CHUNK(mw + 6, 2)
#undef GATHER_CHUNK

    // ---- tail k = 256..287: zero-fill then bond sums (wave owns its rows) ----
    {
        const int mz = mw + (lane >> 3), pz = lane & 7;       // 8 rows x 8 ushort4
        ushort4 zz = {0, 0, 0, 0};
        *(ushort4*)&Afeat[mz * AS + FIN + pz * 4] = zz;
        if (lane < 48) {                                      // 8 rows x 6 feats
            const int r  = lane / 6;
            const int kk = lane - r * 6;
            const int m  = mw + r;
            const float* __restrict__ bb = bonds + ((size_t)(row0 + m)) * (DEG * NBF) + kk;
            const float bv = bb[0] + bb[NBF] + bb[2 * NBF] + bb[3 * NBF] + bb[4 * NBF];
            Afeat[m * AS + FIN + kk] = f2bf(bv);              // same-wave order: wins over zz
        }
    }

    // ---- hoist first B-frag loads above the barrier (hide W latency) ----
    const unsigned short* __restrict__ Wb5 =
        Wsw + (all6 ? (size_t)DEG * FRAG_SHORTS : (size_t)0);
    const int fr = lane & 15;
    const int q  = lane >> 4;
    const int wn = wave * 64;

    bf16x8 b0[4];
    #pragma unroll
    for (int j = 0; j < 4; ++j)
        b0[j] = *(const bf16x8*)&Wb5[((size_t)((wave * 4 + j) * NKT) * 64 + lane) * 8];

    __syncthreads();

    // ---- MFMA pass: wave computes all 32 rows x cols [wave*64, wave*64+64) ----
    auto gemm_pass = [&](const unsigned short* __restrict__ Wb, bf16x8 (&bini)[4],
                         f32x4 (&a)[2][4]) {
        bf16x8 bcur[4], bnxt[4], acur[2], anxt[2];
        #pragma unroll
        for (int j = 0; j < 4; ++j) bcur[j] = bini[j];
        #pragma unroll
        for (int i = 0; i < 2; ++i)
            acur[i] = *(const bf16x8*)&Afeat[(i * 16 + fr) * AS + q * 8];
        #pragma unroll
        for (int t = 0; t < NKT; ++t) {
            if (t + 1 < NKT) {                    // double-buffer both operands
                #pragma unroll
                for (int j = 0; j < 4; ++j)
                    bnxt[j] = *(const bf16x8*)&Wb[((size_t)((wave * 4 + j) * NKT + t + 1) * 64 + lane) * 8];
                #pragma unroll
                for (int i = 0; i < 2; ++i)
                    anxt[i] = *(const bf16x8*)&Afeat[(i * 16 + fr) * AS + (t + 1) * 32 + q * 8];
            }
            #pragma unroll
            for (int i = 0; i < 2; ++i)
                #pragma unroll
                for (int j = 0; j < 4; ++j)
                    a[i][j] = __builtin_amdgcn_mfma_f32_16x16x32_bf16(acur[i], bcur[j], a[i][j], 0, 0, 0);
            if (t + 1 < NKT) {
                #pragma unroll
                for (int j = 0; j < 4; ++j) bcur[j] = bnxt[j];
                #pragma unroll
                for (int i = 0; i < 2; ++i) acur[i] = anxt[i];
            }
        }
    };

    // C/D map: col=lane&15, row=(lane>>4)*4+reg; store rows whose deg == want
    auto epilogue = [&](f32x4 (&a)[2][4], int want) {
        #pragma unroll
        for (int j = 0; j < 4; ++j) {
            const int gn = wn + j * 16 + fr;
            const float bj = bias[gn];
            #pragma unroll
            for (int i = 0; i < 2; ++i) {
                #pragma unroll
                for (int r = 0; r < 4; ++r) {
                    const int lm = i * 16 + q * 4 + r;          // local row
                    if (deg_lds[lm] == want)
                        __builtin_nontemporal_store(sigmoidf_(a[i][j][r] + bj),
                                                    &out[((size_t)row0 + lm) * OOUT + gn]);
                }
            }
        }
    };

    f32x4 acc[2][4];
    #pragma unroll
    for (int i = 0; i < 2; ++i)
        #pragma unroll
        for (int j = 0; j < 4; ++j)
            acc[i][j] = (f32x4){0.f, 0.f, 0.f, 0.f};

    gemm_pass(Wb5, b0, acc);
    epilogue(acc, DEG);

    // ---- odd-degree rows (rare): masked MFMA re-pass per degree present ----
    int dmask = degmask & 0x1F;            // bits 0..4 (block-uniform)
    if (dmask == 0) return;

    if (all6) {
        while (dmask) {
            const int d = __ffs(dmask) - 1;
            dmask &= dmask - 1;
            const unsigned short* __restrict__ Wd = Wsw + (size_t)d * FRAG_SHORTS;
            bf16x8 bd[4];
            #pragma unroll
            for (int j = 0; j < 4; ++j)
                bd[j] = *(const bf16x8*)&Wd[((size_t)((wave * 4 + j) * NKT) * 64 + lane) * 8];
            f32x4 a2[2][4];
            #pragma unroll
            for (int i = 0; i < 2; ++i)
                #pragma unroll
                for (int j = 0; j < 4; ++j)
                    a2[i][j] = (f32x4){0.f, 0.f, 0.f, 0.f};
            gemm_pass(Wd, bd, a2);
            epilogue(a2, d);
        }
    } else {
        // legacy fp32 fixup (only if workspace too small for 6-degree Wsw)
        for (int m = 0; m < MT; ++m) {
            const int dg = deg_lds[m];
            if (dg == DEG) continue;                            // block-uniform branch
            const float* __restrict__ W = degW + (size_t)dg * KDIM * OOUT;
            float s0 = 0.f, s1 = 0.f, s2 = 0.f, s3 = 0.f;
            #pragma unroll 2
            for (int k = 0; k < 260; k += 4) {
                const float w0 = W[(size_t)(k + 0) * OOUT + tid];
                const float w1 = W[(size_t)(k + 1) * OOUT + tid];
                const float w2 = W[(size_t)(k + 2) * OOUT + tid];
                const float w3 = W[(size_t)(k + 3) * OOUT + tid];
                s0 += bf2f(Afeat[m * AS + k + 0]) * w0;
                s1 += bf2f(Afeat[m * AS + k + 1]) * w1;
                s2 += bf2f(Afeat[m * AS + k + 2]) * w2;
                s3 += bf2f(Afeat[m * AS + k + 3]) * w3;
            }
            s0 += bf2f(Afeat[m * AS + 260]) * W[(size_t)260 * OOUT + tid];
            s1 += bf2f(Afeat[m * AS + 261]) * W[(size_t)261 * OOUT + tid];
            const float x = ((s0 + s1) + (s2 + s3)) + bias[tid];
            out[((size_t)row0 + m) * OOUT + tid] = sigmoidf_(x);
        }
    }
}

// ---------------------------------------------------------------------------
// Fallback (R1 fp32 kernel, no workspace) if ws_size is too small.
// ---------------------------------------------------------------------------
#define FMT  32
#define FKT  32
#define FKPAD 288
__global__ __launch_bounds__(256, 2)
void nfp_conv_fallback(const float* __restrict__ atoms, const float* __restrict__ bonds,
                       const int* __restrict__ edges, const float* __restrict__ degW,
                       const float* __restrict__ bias, float* __restrict__ out)
{
    __shared__ float feats[FMT * FKPAD];
    __shared__ float wtile[FKT * OOUT];
    __shared__ int   edg[FMT * DEG];
    __shared__ int   deg_lds[FMT];
    __shared__ int   odd_list[FMT];
    __shared__ int   odd_cnt;
    __shared__ float b_lds[OOUT];

    const int tid = threadIdx.x, bid = blockIdx.x;
    const int batch = bid >> 5, a0 = (bid & 31) * FMT;
    const size_t atom_base = (size_t)batch * NATOMS;

    b_lds[tid] = bias[tid];
    if (tid == 0) odd_cnt = 0;
    if (tid < FMT * DEG) {
        const int m = tid / DEG, d = tid % DEG;
        edg[tid] = edges[(atom_base + a0 + m) * DEG + d];
    }
    __syncthreads();
    if (tid < FMT) {
        int dc = 0;
        #pragma unroll
        for (int d = 0; d < DEG; ++d) dc += (edg[tid * DEG + d] != -1) ? 1 : 0;
        deg_lds[tid] = dc;
        if (dc != DEG) { const int idx = atomicAdd(&odd_cnt, 1); odd_list[idx] = tid; }
    }
    __syncthreads();
    {
        const int f = tid;
        for (int m = 0; m < FMT; ++m) {
            float v = atoms[(atom_base + a0 + m) * FIN + f];
            #pragma unroll
            for (int d = 0; d < DEG; ++d) {
                const int e = edg[m * DEG + d];
                if (e >= 0) v += atoms[(atom_base + e) * FIN + f];
            }
            feats[m * FKPAD + f] = v;
        }
        #pragma unroll
        for (int t = 0; t < 4; ++t) {
            const int idx = t * 256 + tid;
            const int m = idx >> 5, kk = idx & 31;
            float v = 0.f;
            if (kk < NBF) {
                const size_t bb = (atom_base + a0 + m) * (size_t)(DEG * NBF);
                #pragma unroll
                for (int d = 0; d < DEG; ++d) v += bonds[bb + d * NBF + kk];
            }
            feats[m * FKPAD + FIN + kk] = v;
        }
    }
    const float* __restrict__ W5 = degW + (size_t)DEG * KDIM * OOUT;
    float acc[4][8];
    #pragma unroll
    for (int i = 0; i < 4; ++i)
        #pragma unroll
        for (int j = 0; j < 8; ++j) acc[i][j] = 0.f;
    const int tx = tid & 31, ty = tid >> 5;
    for (int kt = 0; kt < FKPAD; kt += FKT) {
        __syncthreads();
        #pragma unroll
        for (int t = 0; t < FKT; ++t) {
            const int k = kt + t;
            wtile[t * OOUT + tid] = (k < KDIM) ? W5[(size_t)k * OOUT + tid] : 0.f;
        }
        __syncthreads();
        #pragma unroll 4
        for (int r = 0; r < FKT; ++r) {
            float a_frag[4];
            #pragma unroll
            for (int i = 0; i < 4; ++i) a_frag[i] = feats[(ty * 4 + i) * FKPAD + kt + r];
            float w_frag[8];
            #pragma unroll
            for (int j = 0; j < 8; ++j) w_frag[j] = wtile[r * OOUT + tx + j * 32];
            #pragma unroll
            for (int i = 0; i < 4; ++i)
                #pragma unroll
                for (int j = 0; j < 8; ++j) acc[i][j] += a_frag[i] * w_frag[j];
        }
    }
    #pragma unroll
    for (int i = 0; i < 4; ++i) {
        const int m = ty * 4 + i;
        if (deg_lds[m] == DEG) {
            const size_t row = (atom_base + a0 + m) * (size_t)OOUT;
            #pragma unroll
            for (int j = 0; j < 8; ++j) {
                const int o = tx + j * 32;
                out[row + o] = sigmoidf_(acc[i][j] + b_lds[o]);
            }
        }
    }
    const int ocnt = odd_cnt;
    for (int i = 0; i < ocnt; ++i) {
        const int m = odd_list[i], d = deg_lds[m];
        const float* __restrict__ W = degW + (size_t)d * KDIM * OOUT;
        float a2 = 0.f;
        for (int k = 0; k < KDIM; ++k) a2 += feats[m * FKPAD + k] * W[(size_t)k * OOUT + tid];
        const size_t row = (atom_base + a0 + m) * (size_t)OOUT;
        out[row + tid] = sigmoidf_(a2 + b_lds[tid]);
    }
}

// ---------------------------------------------------------------------------
extern "C" void kernel_launch(void* const* d_in, const int* in_sizes, int n_in,
                              void* d_out, int out_size, void* d_ws, size_t ws_size,
                              hipStream_t stream) {
    const float* atoms = (const float*)d_in[0];
    const float* bonds = (const float*)d_in[1];
    const int*   edges = (const int*)d_in[2];
    const float* degW  = (const float*)d_in[3];
    const float* bias  = (const float*)d_in[4];
    float* out = (float*)d_out;

    const size_t WSW_ONE = (size_t)FRAG_SHORTS * 2;      // 147,456 B
    const size_t WSW_ALL = (size_t)6 * FRAG_SHORTS * 2;  // 884,736 B

    if (ws_size >= WSW_ALL) {
        unsigned short* Wsw = (unsigned short*)d_ws;
        convert_w_kernel<<<(6 * 16 * NKT * 64 + 255) / 256, 256, 0, stream>>>(degW, Wsw, 1);
        nfp_fused_kernel<<<MROWS / MT, 256, 0, stream>>>(
            atoms, bonds, edges, Wsw, degW, bias, out, 1);
    } else if (ws_size >= WSW_ONE) {
        unsigned short* Wsw = (unsigned short*)d_ws;
        convert_w_kernel<<<(16 * NKT * 64 + 255) / 256, 256, 0, stream>>>(degW, Wsw, 0);
        nfp_fused_kernel<<<MROWS / MT, 256, 0, stream>>>(
            atoms, bonds, edges, Wsw, degW, bias, out, 0);
    } else {
        nfp_conv_fallback<<<BATCH * (NATOMS / FMT), 256, 0, stream>>>(
            atoms, bonds, edges, degW, bias, out);
    }
}